// Round 7
// baseline (839.050 us; speedup 1.0000x reference)
//
#include <hip/hip_runtime.h>
#include <hip/hip_bf16.h>
#include <math.h>

#define D_EMB 512
#define HEADS 8
#define DK 32
#define FKQV 768   // K|V|Q combined output width

typedef __attribute__((ext_vector_type(8))) _Float16 f16x8;
typedef __attribute__((ext_vector_type(4))) float f32x4;

__device__ __forceinline__ unsigned short f2h(float f) {
    _Float16 h = (_Float16)f;
    return __builtin_bit_cast(unsigned short, h);
}
__device__ __forceinline__ float h2f(unsigned short u) {
    return (float)__builtin_bit_cast(_Float16, u);
}

__device__ __forceinline__ void gld_lds16(const void* g, void* l) {
    __builtin_amdgcn_global_load_lds(
        (const __attribute__((address_space(1))) unsigned int*)g,
        (__attribute__((address_space(3))) unsigned int*)l, 16, 0, 0);
}

// ---------------------------------------------------------------------------
// CSR build
// ---------------------------------------------------------------------------
__global__ void count_deg_kernel(const int* __restrict__ recv, int* __restrict__ deg, int M) {
    int e = blockIdx.x * blockDim.x + threadIdx.x;
    if (e < M) atomicAdd(&deg[recv[e]], 1);
}

// per-block inclusive scan (1024/block) -> rowptr[i+1] (pre-carry), bsum[b]
__global__ __launch_bounds__(1024) void scan_block_kernel(const int* __restrict__ deg,
                                                          int* __restrict__ rowptr,
                                                          int* __restrict__ bsum, int n) {
    __shared__ int buf[1024];
    const int i = blockIdx.x * 1024 + threadIdx.x;
    buf[threadIdx.x] = (i < n) ? deg[i] : 0;
    __syncthreads();
    for (int off = 1; off < 1024; off <<= 1) {
        int t = (threadIdx.x >= off) ? buf[threadIdx.x - off] : 0;
        __syncthreads();
        buf[threadIdx.x] += t;
        __syncthreads();
    }
    if (i < n) rowptr[i + 1] = buf[threadIdx.x];
    if (threadIdx.x == 1023) bsum[blockIdx.x] = buf[1023];
}

// exclusive scan of per-block sums (nb <= 64), one wave
__global__ void scan_carry_kernel(int* __restrict__ bsum, int* __restrict__ rowptr, int nb) {
    const int lane = threadIdx.x;  // 0..63
    int v = (lane < nb) ? bsum[lane] : 0;
    const int orig = v;
#pragma unroll
    for (int off = 1; off < 64; off <<= 1) {
        int t = __shfl_up(v, off, 64);
        if (lane >= off) v += t;
    }
    if (lane < nb) bsum[lane] = v - orig;  // exclusive carry
    if (lane == 0) rowptr[0] = 0;
}

__global__ void add_carry_kernel(int* __restrict__ rowptr, const int* __restrict__ bsum, int n) {
    int i = blockIdx.x * blockDim.x + threadIdx.x;
    if (i < n) rowptr[i + 1] += bsum[i >> 10];
}

__global__ void scatter_kernel(const int* __restrict__ recv, const int* __restrict__ send,
                               const int* __restrict__ rowptr, int* __restrict__ cursor,
                               int* __restrict__ ssend, int M) {
    int e = blockIdx.x * blockDim.x + threadIdx.x;
    if (e < M) {
        int r = recv[e];
        int pos = atomicAdd(&cursor[r], 1);
        ssend[rowptr[r] + pos] = send[e];
    }
}

// ---------------------------------------------------------------------------
// Degree-sorted permutation: counting sort by degree (128 buckets)
// ---------------------------------------------------------------------------
__global__ void deg_hist_kernel(const int* __restrict__ rowptr, int* __restrict__ hist, int N) {
    int i = blockIdx.x * blockDim.x + threadIdx.x;
    if (i < N) {
        int d = rowptr[i + 1] - rowptr[i];
        if (d > 127) d = 127;
        atomicAdd(&hist[d], 1);
    }
}

__global__ void hist_scan_kernel(int* __restrict__ hist) {  // 1 block, 128 threads
    __shared__ int buf[128];
    const int t = threadIdx.x;
    buf[t] = hist[t];
    __syncthreads();
    for (int off = 1; off < 128; off <<= 1) {
        int v = (t >= off) ? buf[t - off] : 0;
        __syncthreads();
        buf[t] += v;
        __syncthreads();
    }
    hist[t] = (t == 0) ? 0 : buf[t - 1];  // exclusive
}

__global__ void perm_scatter_kernel(const int* __restrict__ rowptr, int* __restrict__ hist,
                                    int* __restrict__ perm, int N) {
    int i = blockIdx.x * blockDim.x + threadIdx.x;
    if (i < N) {
        int d = rowptr[i + 1] - rowptr[i];
        if (d > 127) d = 127;
        int pos = atomicAdd(&hist[d], 1);
        perm[pos] = i;
    }
}

// ---------------------------------------------------------------------------
// x (fp32) -> fp16, 8 elems/thread
// ---------------------------------------------------------------------------
__global__ void cvt_x_kernel(const float* __restrict__ x, unsigned short* __restrict__ xh, int n8) {
    int i = blockIdx.x * blockDim.x + threadIdx.x;
    if (i >= n8) return;
    const float4 a = ((const float4*)x)[2 * i];
    const float4 b = ((const float4*)x)[2 * i + 1];
    const float v[8] = {a.x, a.y, a.z, a.w, b.x, b.y, b.z, b.w};
    unsigned int u[4];
#pragma unroll
    for (int j = 0; j < 4; j++)
        u[j] = (unsigned int)f2h(v[2 * j]) | ((unsigned int)f2h(v[2 * j + 1]) << 16);
    ((uint4*)xh)[i] = make_uint4(u[0], u[1], u[2], u[3]);
}

// ---------------------------------------------------------------------------
// W[K][F] fp32 -> T[dstRow0+f][k] fp16 (transposed, K-contiguous)
// ---------------------------------------------------------------------------
__global__ __launch_bounds__(256) void transpose_cvt_kernel(
    const float* __restrict__ W, unsigned short* __restrict__ T,
    int K, int F, int dstRow0, int dstStride) {
    __shared__ float tile[32][33];
    const int k0 = blockIdx.x * 32, f0 = blockIdx.y * 32;
    const int tx = threadIdx.x, ty = threadIdx.y;  // 32 x 8
#pragma unroll
    for (int i = 0; i < 4; i++) {
        int kk = ty + 8 * i;
        tile[kk][tx] = W[(size_t)(k0 + kk) * F + f0 + tx];
    }
    __syncthreads();
#pragma unroll
    for (int i = 0; i < 4; i++) {
        int ff = ty + 8 * i;
        T[(size_t)(dstRow0 + f0 + ff) * dstStride + k0 + tx] = f2h(tile[tx][ff]);
    }
}

// bias order matches [K|V|Q] layout
__global__ void bias_pack_kernel(const float* __restrict__ bk, const float* __restrict__ bv,
                                 const float* __restrict__ bq, float* __restrict__ bkvq) {
    int i = threadIdx.x + blockIdx.x * blockDim.x;
    if (i < 256) bkvq[i] = bk[i];
    else if (i < 512) bkvq[i] = bv[i - 256];
    else if (i < 768) bkvq[i] = bq[i - 512];
}

// ---------------------------------------------------------------------------
// fp16 MFMA GEMM: C = A[M,K] @ B^T-stored[F,K] + bias
// Tile 128x128, BK=32, 4 waves (2x2), 4x4 frags of 16x16x32_f16.
// Grid: x = row-block (streams A), y = col-block (B stays L2-hot).
// OUT_MODE: 0 = fp16 out, 2 = fp32 out + fp16 resid
// ---------------------------------------------------------------------------
template<int OUT_MODE, bool RELU>
__global__ __launch_bounds__(256, 4) void gemm_f16_kernel(
    const unsigned short* __restrict__ A, const unsigned short* __restrict__ B,
    const float* __restrict__ bias, const unsigned short* __restrict__ resid,
    void* __restrict__ outp, int Mrows, int Ktot, int F)
{
    __shared__ unsigned short sm[2][2 * 4096];  // [buf][A|B][128*32]

    const int tid = threadIdx.x;
    const int wid = tid >> 6, lane = tid & 63;
    const int wm = wid >> 1, wn = wid & 1;
    const int l15 = lane & 15, kw = lane >> 4;
    const int brow = blockIdx.x * 128, bcol = blockIdx.y * 128;
    const int Mm1 = Mrows - 1;

    // staging: 16 chunks of 1KB (16 rows x 64B); wave w takes chunks w+4i
    const unsigned short* srcs[4];
    int ldsoff[4];
    {
        const int rl = lane >> 2, slot = lane & 3;
#pragma unroll
        for (int i = 0; i < 4; i++) {
            int c = wid + i * 4;
            int s = c >> 3, q = c & 7;
            int row = q * 16 + rl;
            int swz = (slot ^ ((row >> 1) & 3)) * 8;  // pre-swizzled source slot
            const unsigned short* base;
            if (s == 0) { int rg = brow + row; if (rg > Mm1) rg = Mm1; base = A + (size_t)rg * Ktot + swz; }
            else        { base = B + (size_t)(bcol + row) * Ktot + swz; }
            srcs[i] = base;
            ldsoff[i] = s * 4096 + q * 512;
        }
    }

    f32x4 acc[4][4];
#pragma unroll
    for (int a = 0; a < 4; a++)
#pragma unroll
        for (int b = 0; b < 4; b++) acc[a][b] = (f32x4){0.f, 0.f, 0.f, 0.f};

    int aoff[4], boff[4];
#pragma unroll
    for (int f = 0; f < 4; f++) {
        int r = wm * 64 + f * 16 + l15;
        aoff[f] = r * 32 + ((kw ^ ((r >> 1) & 3)) << 3);
        int cn = wn * 64 + f * 16 + l15;
        boff[f] = cn * 32 + ((kw ^ ((cn >> 1) & 3)) << 3);
    }

    const int nt = Ktot / 32;
#pragma unroll
    for (int i = 0; i < 4; i++) gld_lds16(srcs[i], &sm[0][ldsoff[i]]);
    __syncthreads();

    for (int t = 0; t < nt; t++) {
        const unsigned short* sb = &sm[t & 1][0];
        if (t + 1 < nt) {
            unsigned short* db = &sm[(t + 1) & 1][0];
            const int k0 = (t + 1) * 32;
#pragma unroll
            for (int i = 0; i < 4; i++) gld_lds16(srcs[i] + k0, &db[ldsoff[i]]);
        }
        f16x8 ah[4], bh[4];
#pragma unroll
        for (int f = 0; f < 4; f++) {
            ah[f] = *(const f16x8*)&sb[aoff[f]];
            bh[f] = *(const f16x8*)&sb[4096 + boff[f]];
        }
#pragma unroll
        for (int fr = 0; fr < 4; fr++)
#pragma unroll
            for (int fc = 0; fc < 4; fc++)
                acc[fr][fc] = __builtin_amdgcn_mfma_f32_16x16x32_f16(ah[fr], bh[fc], acc[fr][fc], 0, 0, 0);
        __syncthreads();
    }

    // epilogue: C row = kw*4 + j (within 16), col = l15
    float bv4[4];
#pragma unroll
    for (int fc = 0; fc < 4; fc++) bv4[fc] = bias[bcol + wn * 64 + fc * 16 + l15];

#pragma unroll
    for (int fr = 0; fr < 4; fr++) {
#pragma unroll
        for (int j = 0; j < 4; j++) {
            const int row = brow + wm * 64 + fr * 16 + kw * 4 + j;
            if (row >= Mrows) continue;
#pragma unroll
            for (int fc = 0; fc < 4; fc++) {
                const int col = bcol + wn * 64 + fc * 16 + l15;
                float v = acc[fr][fc][j] + bv4[fc];
                if (RELU) v = fmaxf(v, 0.0f);
                const size_t o = (size_t)row * F + col;
                if (OUT_MODE == 0) {
                    ((unsigned short*)outp)[o] = f2h(v);
                } else {
                    ((float*)outp)[o] = v + h2f(resid[o]);
                }
            }
        }
    }
}

// ---------------------------------------------------------------------------
// Fused attention: one lane per (receiver, head), receivers in degree-sorted
// order (perm) so waves have uniform trip counts. kqv layout [K|V|Q]: per
// edge the 8 head-threads fetch one contiguous 1KB (K 512B + V 512B).
// ---------------------------------------------------------------------------
__global__ __launch_bounds__(256) void attn_fused_kernel(
    const unsigned short* __restrict__ kqv, const int* __restrict__ rowptr,
    const int* __restrict__ ssend, const int* __restrict__ perm,
    unsigned short* __restrict__ agg, int N)
{
    const int idx = blockIdx.x * 256 + threadIdx.x;
    const int g = idx >> 3;
    if (g >= N) return;
    const int r = perm[g];
    const int h = idx & 7;

    const unsigned short* qp = kqv + (size_t)r * FKQV + 512 + h * 32;
    const f16x8 q0 = *(const f16x8*)(qp);
    const f16x8 q1 = *(const f16x8*)(qp + 8);
    const f16x8 q2 = *(const f16x8*)(qp + 16);
    const f16x8 q3 = *(const f16x8*)(qp + 24);

    float acc[4][8];
#pragma unroll
    for (int j = 0; j < 4; j++)
#pragma unroll
        for (int i = 0; i < 8; i++) acc[j][i] = 0.0f;
    float denom = 0.0f;

    const int e0 = rowptr[r], e1 = rowptr[r + 1];
    const float scale = 0.17677669529663687f;  // 1/sqrt(32)

    for (int e = e0; e < e1; ++e) {
        const int s = ssend[e];
        const unsigned short* kp = kqv + (size_t)s * FKQV + h * 32;
        const f16x8 k0 = *(const f16x8*)(kp);
        const f16x8 k1 = *(const f16x8*)(kp + 8);
        const f16x8 k2 = *(const f16x8*)(kp + 16);
        const f16x8 k3 = *(const f16x8*)(kp + 24);
        const f16x8 v0 = *(const f16x8*)(kp + 256);
        const f16x8 v1 = *(const f16x8*)(kp + 264);
        const f16x8 v2 = *(const f16x8*)(kp + 272);
        const f16x8 v3 = *(const f16x8*)(kp + 280);

        float d0 = 0.f, d1 = 0.f, d2 = 0.f, d3 = 0.f;
#pragma unroll
        for (int i = 0; i < 8; i++) {
            d0 = fmaf((float)q0[i], (float)k0[i], d0);
            d1 = fmaf((float)q1[i], (float)k1[i], d1);
            d2 = fmaf((float)q2[i], (float)k2[i], d2);
            d3 = fmaf((float)q3[i], (float)k3[i], d3);
        }
        const float a = __expf(((d0 + d1) + (d2 + d3)) * scale);
        denom += a;
#pragma unroll
        for (int i = 0; i < 8; i++) {
            acc[0][i] = fmaf(a, (float)v0[i], acc[0][i]);
            acc[1][i] = fmaf(a, (float)v1[i], acc[1][i]);
            acc[2][i] = fmaf(a, (float)v2[i], acc[2][i]);
            acc[3][i] = fmaf(a, (float)v3[i], acc[3][i]);
        }
    }

    const float inv = (e1 > e0) ? (1.0f / denom) : 0.0f;
    unsigned short* op = agg + (size_t)r * 256 + h * 32;
#pragma unroll
    for (int j = 0; j < 4; j++) {
        f16x8 ov;
#pragma unroll
        for (int i = 0; i < 8; i++) ov[i] = (_Float16)fmaxf(acc[j][i] * inv, 0.0f);
        *(f16x8*)(op + j * 8) = ov;
    }
}

// ---------------------------------------------------------------------------
extern "C" void kernel_launch(void* const* d_in, const int* in_sizes, int n_in,
                              void* d_out, int out_size, void* d_ws, size_t ws_size,
                              hipStream_t stream) {
    const float* x  = (const float*)d_in[0];
    const int* eidx = (const int*)d_in[1];
    const float* Wk = (const float*)d_in[2];
    const float* bk = (const float*)d_in[3];
    const float* Wq = (const float*)d_in[4];
    const float* bq = (const float*)d_in[5];
    const float* Wv = (const float*)d_in[6];
    const float* bv = (const float*)d_in[7];
    const float* Wa = (const float*)d_in[8];
    const float* ba = (const float*)d_in[9];
    const float* Wf = (const float*)d_in[10];
    const float* bf_ = (const float*)d_in[11];
    float* out = (float*)d_out;

    const int N = in_sizes[0] / D_EMB;   // 50000
    const int M = in_sizes[1] / 2;       // 400000
    const int* recv = eidx;
    const int* send = eidx + M;

    // ---- workspace layout ----
    unsigned short* x_h = (unsigned short*)d_ws;             // N*512 (live until Wf resid)
    unsigned short* kqv = x_h + (size_t)N * 512;             // N*768  [K|V|Q]
    unsigned short* agg = kqv + (size_t)N * FKQV;            // N*256
    unsigned short* Wkvq_h = agg + (size_t)N * 256;          // 768*512
    unsigned short* Wat_h  = Wkvq_h + 768 * 512;             // 512*256
    unsigned short* Wft_h  = Wat_h + 512 * 256;              // 512*512
    float* b_kvq = (float*)(Wft_h + 512 * 512);              // 768
    int* rowptr = (int*)(b_kvq + 768);                       // N+1
    int* cursor = rowptr + (N + 1);                          // N
    int* bsum   = cursor + N;                                // 64
    int* hist   = bsum + 64;                                 // 128
    int* perm   = hist + 128;                                // N
    int* ssend  = perm + N;                                  // M
    unsigned short* h1 = kqv;   // alias: kqv dead after attention

    const int nb = (N + 1023) / 1024;  // 49

    // ---- CSR build ----
    hipMemsetAsync(cursor, 0, (size_t)N * sizeof(int), stream);
    count_deg_kernel<<<(M + 255) / 256, 256, 0, stream>>>(recv, cursor, M);
    scan_block_kernel<<<nb, 1024, 0, stream>>>(cursor, rowptr, bsum, N);
    scan_carry_kernel<<<1, 64, 0, stream>>>(bsum, rowptr, nb);
    add_carry_kernel<<<(N + 255) / 256, 256, 0, stream>>>(rowptr, bsum, N);
    hipMemsetAsync(cursor, 0, (size_t)N * sizeof(int), stream);
    scatter_kernel<<<(M + 255) / 256, 256, 0, stream>>>(recv, send, rowptr, cursor, ssend, M);

    // ---- degree-sorted permutation ----
    hipMemsetAsync(hist, 0, 128 * sizeof(int), stream);
    deg_hist_kernel<<<(N + 255) / 256, 256, 0, stream>>>(rowptr, hist, N);
    hist_scan_kernel<<<1, 128, 0, stream>>>(hist);
    perm_scatter_kernel<<<(N + 255) / 256, 256, 0, stream>>>(rowptr, hist, perm, N);

    // ---- input cvt + weight prep ----
    cvt_x_kernel<<<((N * 512 / 8) + 255) / 256, 256, 0, stream>>>(x, x_h, N * 512 / 8);
    {
        dim3 b(32, 8);
        transpose_cvt_kernel<<<dim3(16, 8), b, 0, stream>>>(Wk, Wkvq_h, 512, 256, 0,   512);
        transpose_cvt_kernel<<<dim3(16, 8), b, 0, stream>>>(Wv, Wkvq_h, 512, 256, 256, 512);
        transpose_cvt_kernel<<<dim3(16, 8), b, 0, stream>>>(Wq, Wkvq_h, 512, 256, 512, 512);
        transpose_cvt_kernel<<<dim3(8, 16), b, 0, stream>>>(Wa, Wat_h, 256, 512, 0, 256);
        transpose_cvt_kernel<<<dim3(16, 16), b, 0, stream>>>(Wf, Wft_h, 512, 512, 0, 512);
    }
    bias_pack_kernel<<<3, 256, 0, stream>>>(bk, bv, bq, b_kvq);

    const int gy = (N + 127) / 128;  // 391

    // ---- KVQ = x @ [Wk|Wv|Wq] + b -> fp16 [N][768] ----
    gemm_f16_kernel<0, false><<<dim3(gy, FKQV / 128), 256, 0, stream>>>(
        x_h, Wkvq_h, b_kvq, nullptr, kqv, N, 512, FKQV);

    // ---- fused attention gather -> agg fp16 [N][256] ----
    attn_fused_kernel<<<(N * HEADS + 255) / 256, 256, 0, stream>>>(
        kqv, rowptr, ssend, perm, agg, N);

    // ---- h1 = relu(agg @ Wa + ba) -> fp16 [N][512] (into kqv region) ----
    gemm_f16_kernel<0, true><<<dim3(gy, 4), 256, 0, stream>>>(
        agg, Wat_h, ba, nullptr, h1, N, 256, 512);

    // ---- out = x_h + relu(h1 @ Wf + bf) -> fp32 ----
    gemm_f16_kernel<2, true><<<dim3(gy, 4), 256, 0, stream>>>(
        h1, Wft_h, bf_, x_h, out, N, 512, 512);
}

// Round 8
// 506.311 us; speedup vs baseline: 1.6572x; 1.6572x over previous
//
#include <hip/hip_runtime.h>
#include <hip/hip_bf16.h>
#include <math.h>

#define D_EMB 512
#define HEADS 8
#define DK 32
#define FKQV 768   // K|V|Q combined output width

typedef __attribute__((ext_vector_type(8))) _Float16 f16x8;
typedef __attribute__((ext_vector_type(4))) float f32x4;

__device__ __forceinline__ unsigned short f2h(float f) {
    _Float16 h = (_Float16)f;
    return __builtin_bit_cast(unsigned short, h);
}
__device__ __forceinline__ float h2f(unsigned short u) {
    return (float)__builtin_bit_cast(_Float16, u);
}

__device__ __forceinline__ void gld_lds16(const void* g, void* l) {
    __builtin_amdgcn_global_load_lds(
        (const __attribute__((address_space(1))) unsigned int*)g,
        (__attribute__((address_space(3))) unsigned int*)l, 16, 0, 0);
}

// ---------------------------------------------------------------------------
// CSR build
// ---------------------------------------------------------------------------
__global__ void count_deg_kernel(const int* __restrict__ recv, int* __restrict__ deg, int M) {
    int e = blockIdx.x * blockDim.x + threadIdx.x;
    if (e < M) atomicAdd(&deg[recv[e]], 1);
}

// per-block inclusive scan (1024/block) -> rowptr[i+1] (pre-carry), bsum[b]
__global__ __launch_bounds__(1024) void scan_block_kernel(const int* __restrict__ deg,
                                                          int* __restrict__ rowptr,
                                                          int* __restrict__ bsum, int n) {
    __shared__ int buf[1024];
    const int i = blockIdx.x * 1024 + threadIdx.x;
    buf[threadIdx.x] = (i < n) ? deg[i] : 0;
    __syncthreads();
    for (int off = 1; off < 1024; off <<= 1) {
        int t = (threadIdx.x >= off) ? buf[threadIdx.x - off] : 0;
        __syncthreads();
        buf[threadIdx.x] += t;
        __syncthreads();
    }
    if (i < n) rowptr[i + 1] = buf[threadIdx.x];
    if (threadIdx.x == 1023) bsum[blockIdx.x] = buf[1023];
}

// exclusive scan of per-block sums (nb <= 64), one wave
__global__ void scan_carry_kernel(int* __restrict__ bsum, int* __restrict__ rowptr, int nb) {
    const int lane = threadIdx.x;  // 0..63
    int v = (lane < nb) ? bsum[lane] : 0;
    const int orig = v;
#pragma unroll
    for (int off = 1; off < 64; off <<= 1) {
        int t = __shfl_up(v, off, 64);
        if (lane >= off) v += t;
    }
    if (lane < nb) bsum[lane] = v - orig;  // exclusive carry
    if (lane == 0) rowptr[0] = 0;
}

__global__ void add_carry_kernel(int* __restrict__ rowptr, const int* __restrict__ bsum, int n) {
    int i = blockIdx.x * blockDim.x + threadIdx.x;
    if (i < n) rowptr[i + 1] += bsum[i >> 10];
}

__global__ void scatter_kernel(const int* __restrict__ recv, const int* __restrict__ send,
                               const int* __restrict__ rowptr, int* __restrict__ cursor,
                               int* __restrict__ ssend, int M) {
    int e = blockIdx.x * blockDim.x + threadIdx.x;
    if (e < M) {
        int r = recv[e];
        int pos = atomicAdd(&cursor[r], 1);
        ssend[rowptr[r] + pos] = send[e];
    }
}

// ---------------------------------------------------------------------------
// Degree-sorted permutation — contention-free counting sort.
// blockhist[d * NBH + b] = #nodes with degree-bucket d in hist-block b.
// ---------------------------------------------------------------------------
__global__ __launch_bounds__(1024) void deg_hist_block_kernel(
    const int* __restrict__ rowptr, int* __restrict__ blockhist, int N, int NBH) {
    __shared__ int h[128];
    if (threadIdx.x < 128) h[threadIdx.x] = 0;
    __syncthreads();
    const int i = blockIdx.x * 1024 + threadIdx.x;
    if (i < N) {
        int d = rowptr[i + 1] - rowptr[i];
        if (d > 127) d = 127;
        atomicAdd(&h[d], 1);   // LDS atomic — low cost
    }
    __syncthreads();
    if (threadIdx.x < 128) blockhist[threadIdx.x * NBH + blockIdx.x] = h[threadIdx.x];
}

// single-block exclusive scan over n (<= ~8k) ints, in place
__global__ __launch_bounds__(1024) void scan_small_kernel(int* __restrict__ a, int n) {
    __shared__ int buf[1024];
    __shared__ int carry_s;
    if (threadIdx.x == 0) carry_s = 0;
    __syncthreads();
    for (int base = 0; base < n; base += 1024) {
        const int i = base + threadIdx.x;
        const int v = (i < n) ? a[i] : 0;
        buf[threadIdx.x] = v;
        __syncthreads();
        for (int off = 1; off < 1024; off <<= 1) {
            int t = (threadIdx.x >= off) ? buf[threadIdx.x - off] : 0;
            __syncthreads();
            buf[threadIdx.x] += t;
            __syncthreads();
        }
        if (i < n) a[i] = carry_s + buf[threadIdx.x] - v;  // exclusive
        __syncthreads();
        if (threadIdx.x == 1023) carry_s += buf[1023];
        __syncthreads();
    }
}

__global__ __launch_bounds__(1024) void perm_scatter_block_kernel(
    const int* __restrict__ rowptr, const int* __restrict__ offs,
    int* __restrict__ perm, int N, int NBH) {
    __shared__ int h[128];
    if (threadIdx.x < 128) h[threadIdx.x] = 0;
    __syncthreads();
    const int i = blockIdx.x * 1024 + threadIdx.x;
    if (i < N) {
        int d = rowptr[i + 1] - rowptr[i];
        if (d > 127) d = 127;
        int local = atomicAdd(&h[d], 1);  // LDS-local rank
        perm[offs[d * NBH + blockIdx.x] + local] = i;
    }
}

// ---------------------------------------------------------------------------
// x (fp32) -> fp16, 8 elems/thread
// ---------------------------------------------------------------------------
__global__ void cvt_x_kernel(const float* __restrict__ x, unsigned short* __restrict__ xh, int n8) {
    int i = blockIdx.x * blockDim.x + threadIdx.x;
    if (i >= n8) return;
    const float4 a = ((const float4*)x)[2 * i];
    const float4 b = ((const float4*)x)[2 * i + 1];
    const float v[8] = {a.x, a.y, a.z, a.w, b.x, b.y, b.z, b.w};
    unsigned int u[4];
#pragma unroll
    for (int j = 0; j < 4; j++)
        u[j] = (unsigned int)f2h(v[2 * j]) | ((unsigned int)f2h(v[2 * j + 1]) << 16);
    ((uint4*)xh)[i] = make_uint4(u[0], u[1], u[2], u[3]);
}

// ---------------------------------------------------------------------------
// W[K][F] fp32 -> T[dstRow0+f][k] fp16 (transposed, K-contiguous)
// ---------------------------------------------------------------------------
__global__ __launch_bounds__(256) void transpose_cvt_kernel(
    const float* __restrict__ W, unsigned short* __restrict__ T,
    int K, int F, int dstRow0, int dstStride) {
    __shared__ float tile[32][33];
    const int k0 = blockIdx.x * 32, f0 = blockIdx.y * 32;
    const int tx = threadIdx.x, ty = threadIdx.y;  // 32 x 8
#pragma unroll
    for (int i = 0; i < 4; i++) {
        int kk = ty + 8 * i;
        tile[kk][tx] = W[(size_t)(k0 + kk) * F + f0 + tx];
    }
    __syncthreads();
#pragma unroll
    for (int i = 0; i < 4; i++) {
        int ff = ty + 8 * i;
        T[(size_t)(dstRow0 + f0 + ff) * dstStride + k0 + tx] = f2h(tile[tx][ff]);
    }
}

// bias order matches [K|V|Q] layout
__global__ void bias_pack_kernel(const float* __restrict__ bk, const float* __restrict__ bv,
                                 const float* __restrict__ bq, float* __restrict__ bkvq) {
    int i = threadIdx.x + blockIdx.x * blockDim.x;
    if (i < 256) bkvq[i] = bk[i];
    else if (i < 512) bkvq[i] = bv[i - 256];
    else if (i < 768) bkvq[i] = bq[i - 512];
}

// ---------------------------------------------------------------------------
// fp16 MFMA GEMM: C = A[M,K] @ B^T-stored[F,K] + bias
// Tile 128x128, BK=32, 4 waves (2x2), 4x4 frags of 16x16x32_f16.
// Grid (round-6 measured config): x = col-block, y = row-block.
// OUT_MODE: 0 = fp16 out, 2 = fp32 out + fp16 resid
// ---------------------------------------------------------------------------
template<int OUT_MODE, bool RELU>
__global__ __launch_bounds__(256, 4) void gemm_f16_kernel(
    const unsigned short* __restrict__ A, const unsigned short* __restrict__ B,
    const float* __restrict__ bias, const unsigned short* __restrict__ resid,
    void* __restrict__ outp, int Mrows, int Ktot, int F)
{
    __shared__ unsigned short sm[2][2 * 4096];  // [buf][A|B][128*32]

    const int tid = threadIdx.x;
    const int wid = tid >> 6, lane = tid & 63;
    const int wm = wid >> 1, wn = wid & 1;
    const int l15 = lane & 15, kw = lane >> 4;
    const int brow = blockIdx.y * 128, bcol = blockIdx.x * 128;
    const int Mm1 = Mrows - 1;

    // staging: 16 chunks of 1KB (16 rows x 64B); wave w takes chunks w+4i
    const unsigned short* srcs[4];
    int ldsoff[4];
    {
        const int rl = lane >> 2, slot = lane & 3;
#pragma unroll
        for (int i = 0; i < 4; i++) {
            int c = wid + i * 4;
            int s = c >> 3, q = c & 7;
            int row = q * 16 + rl;
            int swz = (slot ^ ((row >> 1) & 3)) * 8;  // pre-swizzled source slot
            const unsigned short* base;
            if (s == 0) { int rg = brow + row; if (rg > Mm1) rg = Mm1; base = A + (size_t)rg * Ktot + swz; }
            else        { base = B + (size_t)(bcol + row) * Ktot + swz; }
            srcs[i] = base;
            ldsoff[i] = s * 4096 + q * 512;
        }
    }

    f32x4 acc[4][4];
#pragma unroll
    for (int a = 0; a < 4; a++)
#pragma unroll
        for (int b = 0; b < 4; b++) acc[a][b] = (f32x4){0.f, 0.f, 0.f, 0.f};

    int aoff[4], boff[4];
#pragma unroll
    for (int f = 0; f < 4; f++) {
        int r = wm * 64 + f * 16 + l15;
        aoff[f] = r * 32 + ((kw ^ ((r >> 1) & 3)) << 3);
        int cn = wn * 64 + f * 16 + l15;
        boff[f] = cn * 32 + ((kw ^ ((cn >> 1) & 3)) << 3);
    }

    const int nt = Ktot / 32;
#pragma unroll
    for (int i = 0; i < 4; i++) gld_lds16(srcs[i], &sm[0][ldsoff[i]]);
    __syncthreads();

    for (int t = 0; t < nt; t++) {
        const unsigned short* sb = &sm[t & 1][0];
        if (t + 1 < nt) {
            unsigned short* db = &sm[(t + 1) & 1][0];
            const int k0 = (t + 1) * 32;
#pragma unroll
            for (int i = 0; i < 4; i++) gld_lds16(srcs[i] + k0, &db[ldsoff[i]]);
        }
        f16x8 ah[4], bh[4];
#pragma unroll
        for (int f = 0; f < 4; f++) {
            ah[f] = *(const f16x8*)&sb[aoff[f]];
            bh[f] = *(const f16x8*)&sb[4096 + boff[f]];
        }
#pragma unroll
        for (int fr = 0; fr < 4; fr++)
#pragma unroll
            for (int fc = 0; fc < 4; fc++)
                acc[fr][fc] = __builtin_amdgcn_mfma_f32_16x16x32_f16(ah[fr], bh[fc], acc[fr][fc], 0, 0, 0);
        __syncthreads();
    }

    // epilogue: C row = kw*4 + j (within 16), col = l15
    float bv4[4];
#pragma unroll
    for (int fc = 0; fc < 4; fc++) bv4[fc] = bias[bcol + wn * 64 + fc * 16 + l15];

#pragma unroll
    for (int fr = 0; fr < 4; fr++) {
#pragma unroll
        for (int j = 0; j < 4; j++) {
            const int row = brow + wm * 64 + fr * 16 + kw * 4 + j;
            if (row >= Mrows) continue;
#pragma unroll
            for (int fc = 0; fc < 4; fc++) {
                const int col = bcol + wn * 64 + fc * 16 + l15;
                float v = acc[fr][fc][j] + bv4[fc];
                if (RELU) v = fmaxf(v, 0.0f);
                const size_t o = (size_t)row * F + col;
                if (OUT_MODE == 0) {
                    ((unsigned short*)outp)[o] = f2h(v);
                } else {
                    ((float*)outp)[o] = v + h2f(resid[o]);
                }
            }
        }
    }
}

// ---------------------------------------------------------------------------
// Fused attention: one lane per (receiver, head), receivers in degree-sorted
// order (perm) so waves have uniform trip counts. kqv layout [K|V|Q]: per
// edge the 8 head-threads fetch one contiguous 1KB (K 512B + V 512B).
// ---------------------------------------------------------------------------
__global__ __launch_bounds__(256) void attn_fused_kernel(
    const unsigned short* __restrict__ kqv, const int* __restrict__ rowptr,
    const int* __restrict__ ssend, const int* __restrict__ perm,
    unsigned short* __restrict__ agg, int N)
{
    const int idx = blockIdx.x * 256 + threadIdx.x;
    const int g = idx >> 3;
    if (g >= N) return;
    const int r = perm[g];
    const int h = idx & 7;

    const unsigned short* qp = kqv + (size_t)r * FKQV + 512 + h * 32;
    const f16x8 q0 = *(const f16x8*)(qp);
    const f16x8 q1 = *(const f16x8*)(qp + 8);
    const f16x8 q2 = *(const f16x8*)(qp + 16);
    const f16x8 q3 = *(const f16x8*)(qp + 24);

    float acc[4][8];
#pragma unroll
    for (int j = 0; j < 4; j++)
#pragma unroll
        for (int i = 0; i < 8; i++) acc[j][i] = 0.0f;
    float denom = 0.0f;

    const int e0 = rowptr[r], e1 = rowptr[r + 1];
    const float scale = 0.17677669529663687f;  // 1/sqrt(32)

    for (int e = e0; e < e1; ++e) {
        const int s = ssend[e];
        const unsigned short* kp = kqv + (size_t)s * FKQV + h * 32;
        const f16x8 k0 = *(const f16x8*)(kp);
        const f16x8 k1 = *(const f16x8*)(kp + 8);
        const f16x8 k2 = *(const f16x8*)(kp + 16);
        const f16x8 k3 = *(const f16x8*)(kp + 24);
        const f16x8 v0 = *(const f16x8*)(kp + 256);
        const f16x8 v1 = *(const f16x8*)(kp + 264);
        const f16x8 v2 = *(const f16x8*)(kp + 272);
        const f16x8 v3 = *(const f16x8*)(kp + 280);

        float d0 = 0.f, d1 = 0.f, d2 = 0.f, d3 = 0.f;
#pragma unroll
        for (int i = 0; i < 8; i++) {
            d0 = fmaf((float)q0[i], (float)k0[i], d0);
            d1 = fmaf((float)q1[i], (float)k1[i], d1);
            d2 = fmaf((float)q2[i], (float)k2[i], d2);
            d3 = fmaf((float)q3[i], (float)k3[i], d3);
        }
        const float a = __expf(((d0 + d1) + (d2 + d3)) * scale);
        denom += a;
#pragma unroll
        for (int i = 0; i < 8; i++) {
            acc[0][i] = fmaf(a, (float)v0[i], acc[0][i]);
            acc[1][i] = fmaf(a, (float)v1[i], acc[1][i]);
            acc[2][i] = fmaf(a, (float)v2[i], acc[2][i]);
            acc[3][i] = fmaf(a, (float)v3[i], acc[3][i]);
        }
    }

    const float inv = (e1 > e0) ? (1.0f / denom) : 0.0f;
    unsigned short* op = agg + (size_t)r * 256 + h * 32;
#pragma unroll
    for (int j = 0; j < 4; j++) {
        f16x8 ov;
#pragma unroll
        for (int i = 0; i < 8; i++) ov[i] = (_Float16)fmaxf(acc[j][i] * inv, 0.0f);
        *(f16x8*)(op + j * 8) = ov;
    }
}

// ---------------------------------------------------------------------------
extern "C" void kernel_launch(void* const* d_in, const int* in_sizes, int n_in,
                              void* d_out, int out_size, void* d_ws, size_t ws_size,
                              hipStream_t stream) {
    const float* x  = (const float*)d_in[0];
    const int* eidx = (const int*)d_in[1];
    const float* Wk = (const float*)d_in[2];
    const float* bk = (const float*)d_in[3];
    const float* Wq = (const float*)d_in[4];
    const float* bq = (const float*)d_in[5];
    const float* Wv = (const float*)d_in[6];
    const float* bv = (const float*)d_in[7];
    const float* Wa = (const float*)d_in[8];
    const float* ba = (const float*)d_in[9];
    const float* Wf = (const float*)d_in[10];
    const float* bf_ = (const float*)d_in[11];
    float* out = (float*)d_out;

    const int N = in_sizes[0] / D_EMB;   // 50000
    const int M = in_sizes[1] / 2;       // 400000
    const int* recv = eidx;
    const int* send = eidx + M;

    const int NBH = (N + 1023) / 1024;   // 49 hist blocks

    // ---- workspace layout ----
    unsigned short* x_h = (unsigned short*)d_ws;             // N*512 (live until Wf resid)
    unsigned short* kqv = x_h + (size_t)N * 512;             // N*768  [K|V|Q]
    unsigned short* agg = kqv + (size_t)N * FKQV;            // N*256
    unsigned short* Wkvq_h = agg + (size_t)N * 256;          // 768*512
    unsigned short* Wat_h  = Wkvq_h + 768 * 512;             // 512*256
    unsigned short* Wft_h  = Wat_h + 512 * 256;              // 512*512
    float* b_kvq = (float*)(Wft_h + 512 * 512);              // 768
    int* rowptr = (int*)(b_kvq + 768);                       // N+1
    int* cursor = rowptr + (N + 1);                          // N
    int* bsum   = cursor + N;                                // 64
    int* blockhist = bsum + 64;                              // 128*NBH (<=8192)
    int* perm   = blockhist + 8192;                          // N
    int* ssend  = perm + N;                                  // M
    unsigned short* h1 = kqv;   // alias: kqv dead after attention

    const int nb = (N + 1023) / 1024;  // 49

    // ---- CSR build ----
    hipMemsetAsync(cursor, 0, (size_t)N * sizeof(int), stream);
    count_deg_kernel<<<(M + 255) / 256, 256, 0, stream>>>(recv, cursor, M);
    scan_block_kernel<<<nb, 1024, 0, stream>>>(cursor, rowptr, bsum, N);
    scan_carry_kernel<<<1, 64, 0, stream>>>(bsum, rowptr, nb);
    add_carry_kernel<<<(N + 255) / 256, 256, 0, stream>>>(rowptr, bsum, N);
    hipMemsetAsync(cursor, 0, (size_t)N * sizeof(int), stream);
    scatter_kernel<<<(M + 255) / 256, 256, 0, stream>>>(recv, send, rowptr, cursor, ssend, M);

    // ---- degree-sorted permutation (contention-free counting sort) ----
    deg_hist_block_kernel<<<NBH, 1024, 0, stream>>>(rowptr, blockhist, N, NBH);
    scan_small_kernel<<<1, 1024, 0, stream>>>(blockhist, 128 * NBH);
    perm_scatter_block_kernel<<<NBH, 1024, 0, stream>>>(rowptr, blockhist, perm, N, NBH);

    // ---- input cvt + weight prep ----
    cvt_x_kernel<<<((N * 512 / 8) + 255) / 256, 256, 0, stream>>>(x, x_h, N * 512 / 8);
    {
        dim3 b(32, 8);
        transpose_cvt_kernel<<<dim3(16, 8), b, 0, stream>>>(Wk, Wkvq_h, 512, 256, 0,   512);
        transpose_cvt_kernel<<<dim3(16, 8), b, 0, stream>>>(Wv, Wkvq_h, 512, 256, 256, 512);
        transpose_cvt_kernel<<<dim3(16, 8), b, 0, stream>>>(Wq, Wkvq_h, 512, 256, 512, 512);
        transpose_cvt_kernel<<<dim3(8, 16), b, 0, stream>>>(Wa, Wat_h, 256, 512, 0, 256);
        transpose_cvt_kernel<<<dim3(16, 16), b, 0, stream>>>(Wf, Wft_h, 512, 512, 0, 512);
    }
    bias_pack_kernel<<<3, 256, 0, stream>>>(bk, bv, bq, b_kvq);

    const int gy = (N + 127) / 128;  // 391

    // ---- KVQ = x @ [Wk|Wv|Wq] + b -> fp16 [N][768] ----
    gemm_f16_kernel<0, false><<<dim3(FKQV / 128, gy), 256, 0, stream>>>(
        x_h, Wkvq_h, b_kvq, nullptr, kqv, N, 512, FKQV);

    // ---- fused attention gather -> agg fp16 [N][256] ----
    attn_fused_kernel<<<(N * HEADS + 255) / 256, 256, 0, stream>>>(
        kqv, rowptr, ssend, perm, agg, N);

    // ---- h1 = relu(agg @ Wa + ba) -> fp16 [N][512] (into kqv region) ----
    gemm_f16_kernel<0, true><<<dim3(4, gy), 256, 0, stream>>>(
        agg, Wat_h, ba, nullptr, h1, N, 256, 512);

    // ---- out = x_h + relu(h1 @ Wf + bf) -> fp32 ----
    gemm_f16_kernel<2, true><<<dim3(4, gy), 256, 0, stream>>>(
        h1, Wft_h, bf_, x_h, out, N, 512, 512);
}